// Round 14
// baseline (245.062 us; speedup 1.0000x reference)
//
#include <hip/hip_runtime.h>

#define NN 50000
#define NE 400000

typedef unsigned short u16;
typedef unsigned int   u32;
typedef __bf16 bf16x4 __attribute__((ext_vector_type(4)));
typedef __bf16 bf16x8 __attribute__((ext_vector_type(8)));
typedef float  f32x16 __attribute__((ext_vector_type(16)));

union ABFrag { bf16x8 v; bf16x4 h[2]; };
union BFrag  { uint4 u; bf16x8 v; };

__device__ __forceinline__ u16 f2bfu(float f) {
  u32 u = __builtin_bit_cast(u32, f);
  return (u16)((u + 0x7FFFu + ((u >> 16) & 1u)) >> 16);  // RNE f32->bf16
}
__device__ __forceinline__ float bf2f(u16 u) {
  return __builtin_bit_cast(float, (u32)u << 16);
}

// ---------------- prep: cvt + weight-pack + hist in ONE launch ---------------
// Pack for mfma_f32_32x32x16_bf16 B-operand:
// P[((t16*256+n)*2+h)*8+j] = W[16*t16 + 4h + (j&3) + 8*(j>>2)][n]
__device__ __forceinline__ void pack_one(const float* __restrict__ W,
                                         u16* __restrict__ P, int idx) {
  int k = idx >> 8, n = idx & 255;
  int t16 = k >> 4, kp = k & 15;
  int hh = (kp >> 2) & 1;
  int j = (kp & 3) | (((kp >> 3) & 1) << 2);
  P[(((t16 << 8) + n) << 4) + (hh << 3) + j] = f2bfu(W[idx]);
}

#define NB_CVT  12500
#define NB_PACK 1088
#define NB_HIST 1563

__global__ __launch_bounds__(256) void k_prep(
    const float* __restrict__ nodes, u16* __restrict__ nodes_bf,
    const float* __restrict__ Wm, const float* __restrict__ W0,
    const float* __restrict__ W1, const float* __restrict__ W2,
    u16* __restrict__ Pm, u16* __restrict__ P0,
    u16* __restrict__ P1, u16* __restrict__ P2,
    const int* __restrict__ recv, int* __restrict__ cnt)
{
  int b = blockIdx.x, t = threadIdx.x;
  if (b < NB_CVT) {
    int i = b * 256 + t;
    float4 f = ((const float4*)nodes)[i];
    ushort4 o;
    o.x = f2bfu(f.x); o.y = f2bfu(f.y); o.z = f2bfu(f.z); o.w = f2bfu(f.w);
    ((ushort4*)nodes_bf)[i] = o;
  } else if (b < NB_CVT + NB_PACK) {
    int idx = (b - NB_CVT) * 256 + t;
    const int S0 = 320 * 256, S1 = S0 + 65536, S2 = S1 + 65536;
    if (idx < S0)      pack_one(Wm, Pm, idx);
    else if (idx < S1) pack_one(W0, P0, idx - S0);
    else if (idx < S2) pack_one(W1, P1, idx - S1);
    else               pack_one(W2, P2, idx - S2);
  } else {
    int i = (b - NB_CVT - NB_PACK) * 256 + t;
    if (i < NE) atomicAdd(&cnt[recv[i]], 1);
  }
}

// ---------------- counting-sort scan + scatter -------------------------------
__global__ __launch_bounds__(256) void k_scan1(const int* __restrict__ cnt,
                                               int* __restrict__ loc,
                                               int* __restrict__ bsum) {
  __shared__ int sm[256];
  int t = threadIdx.x, i = blockIdx.x * 256 + t;
  int v = (i < NN) ? cnt[i] : 0;
  sm[t] = v;
  __syncthreads();
  #pragma unroll
  for (int d = 1; d < 256; d <<= 1) {
    int x = sm[t];
    int y = (t >= d) ? sm[t - d] : 0;
    __syncthreads();
    sm[t] = x + y;
    __syncthreads();
  }
  if (i < NN) loc[i] = sm[t] - v;
  if (t == 255) bsum[blockIdx.x] = sm[255];
}

__global__ __launch_bounds__(256) void k_scan2(int* __restrict__ bsum,
                                               int* __restrict__ bpre, int nb) {
  __shared__ int sm[256];
  int t = threadIdx.x;
  int v = (t < nb) ? bsum[t] : 0;
  sm[t] = v;
  __syncthreads();
  #pragma unroll
  for (int d = 1; d < 256; d <<= 1) {
    int x = sm[t];
    int y = (t >= d) ? sm[t - d] : 0;
    __syncthreads();
    sm[t] = x + y;
    __syncthreads();
  }
  if (t < nb) bpre[t] = sm[t] - v;
}

__global__ __launch_bounds__(256) void k_scan3(const int* __restrict__ loc,
                                               const int* __restrict__ bpre,
                                               int* __restrict__ offs,
                                               int* __restrict__ cursor) {
  int i = blockIdx.x * 256 + threadIdx.x;
  if (i < NN) {
    int o = loc[i] + bpre[blockIdx.x];
    offs[i] = o;
    cursor[i] = o;
  }
  if (i == NN - 1) offs[NN] = NE;
}

__global__ __launch_bounds__(256) void k_scatter(
    const int* __restrict__ snd, const int* __restrict__ recv,
    int* __restrict__ cursor, int2* __restrict__ s_pair) {
  int e = blockIdx.x * 256 + threadIdx.x;
  if (e < NE) {
    int p = atomicAdd(&cursor[recv[e]], 1);
    int2 pr; pr.x = snd[e]; pr.y = e;
    s_pair[p] = pr;
  }
}

// ---------------- aggregation: half-wave paired volleys (R13, at floor) ------
__global__ __launch_bounds__(256) void k_aggr(
    const u16* __restrict__ nodes_bf, const float* __restrict__ edges,
    const int* __restrict__ offs, const int2* __restrict__ s_pair,
    u16* __restrict__ X)
{
  const int node = blockIdx.x * 4 + (threadIdx.x >> 6);
  const int lane = threadIdx.x & 63;
  const int h = lane >> 5, c = lane & 31;
  const int beg = offs[node], end = offs[node + 1];

  float a0 = 0.f, a1 = 0.f, a2 = 0.f, a3 = 0.f;
  float a4 = 0.f, a5 = 0.f, a6 = 0.f, a7 = 0.f;
  float ae0 = 0.f, ae1 = 0.f;

  for (int jb = beg; jb < end; jb += 8) {
    int j = jb + (lane & 7);
    if (j >= end) j = end - 1;
    int2 pr = s_pair[j];
    const int rem = end - jb;

#define PGATHER(K) \
    int s##K = __shfl(pr.x, 2 * K + h); \
    int e##K = __shfl(pr.y, 2 * K + h); \
    uint4 n##K = *(const uint4*)(nodes_bf + (size_t)s##K * 256 + (c << 3)); \
    float2 v##K = *(const float2*)(edges + (size_t)e##K * 64 + (c << 1));

    PGATHER(0) PGATHER(1) PGATHER(2) PGATHER(3)
#undef PGATHER

#define PACC(K) \
    if (rem > 2 * K + h) { \
      a0 += bf2f((u16)n##K.x); a1 += bf2f((u16)(n##K.x >> 16)); \
      a2 += bf2f((u16)n##K.y); a3 += bf2f((u16)(n##K.y >> 16)); \
      a4 += bf2f((u16)n##K.z); a5 += bf2f((u16)(n##K.z >> 16)); \
      a6 += bf2f((u16)n##K.w); a7 += bf2f((u16)(n##K.w >> 16)); \
      ae0 += v##K.x; ae1 += v##K.y; }

    PACC(0) PACC(1) PACC(2) PACC(3)
#undef PACC
  }

  a0 += __shfl_xor(a0, 32); a1 += __shfl_xor(a1, 32);
  a2 += __shfl_xor(a2, 32); a3 += __shfl_xor(a3, 32);
  a4 += __shfl_xor(a4, 32); a5 += __shfl_xor(a5, 32);
  a6 += __shfl_xor(a6, 32); a7 += __shfl_xor(a7, 32);
  ae0 += __shfl_xor(ae0, 32); ae1 += __shfl_xor(ae1, 32);

  if (lane < 32) {
    u16* xr = X + (size_t)node * 320;
    uint4 o;
    o.x = (u32)f2bfu(a0) | ((u32)f2bfu(a1) << 16);
    o.y = (u32)f2bfu(a2) | ((u32)f2bfu(a3) << 16);
    o.z = (u32)f2bfu(a4) | ((u32)f2bfu(a5) << 16);
    o.w = (u32)f2bfu(a6) | ((u32)f2bfu(a7) << 16);
    *(uint4*)(xr + (c << 3)) = o;
    *(u32*)(xr + 256 + (c << 1)) =
        (u32)f2bfu(ae0) | ((u32)f2bfu(ae1) << 16);
  }
}

// ---------------- fused dense chain: 32x32x16 MFMA (halved LDS B/MAC) --------
// 512 threads = 8 waves: wr = w>>2 (32-row half), wc = w&3 (64-col quarter).
// acc = 2 x f32x16 (col-blocks cb0/cb1) = 32 VGPRs; live set ~58 < 64-tier.
// LDS ~60 KB -> 2 blocks/CU: one block's barrier drain overlaps the other's
// MFMA phase. C/D layout: col=lane&31, row=(reg&3)+8*(reg>>2)+4*(lane>>5).

#define AT_ADDR(r, c) (atb + ((((r) * 640) + ((c) * 2)) ^ (((r) & 7) << 4)))

#define WRBT32(c, v) do { int _c = (c); \
  *(uint4*)&Bt[((_c >> 9) << 12) + ((_c & 1) << 11) + (((_c >> 1) & 255) << 3)] = (v); \
} while (0)

#define MFMA_STEP32(t) \
  _Pragma("unroll") \
  for (int s = 0; s < 2; ++s) { \
    ABFrag a; \
    const int kc = ((t) << 5) + (s << 4) + (h << 2); \
    a.h[0] = *(const bf16x4*)AT_ADDR(mrow, kc); \
    a.h[1] = *(const bf16x4*)AT_ADDR(mrow, kc + 8); \
    const int bi = (s << 12) + (h << 11) + ((wcn + m32) << 3); \
    BFrag bA, bB; \
    bA.u = *(const uint4*)&Bt[bi]; \
    bB.u = *(const uint4*)&Bt[bi + 256]; \
    accA = __builtin_amdgcn_mfma_f32_32x32x16_bf16(a.v, bA.v, accA, 0, 0, 0); \
    accB = __builtin_amdgcn_mfma_f32_32x32x16_bf16(a.v, bB.v, accB, 0, 0, 0); \
  }

#define RUN_LAYER32(wp, T) do { \
  const u16* pb = (wp) + ((size_t)tid << 3); \
  uint4 p0 = *(const uint4*)(pb); \
  uint4 p1 = *(const uint4*)(pb + 4096); \
  _Pragma("unroll 1") \
  for (int t = 0; t < (T); ++t) { \
    __syncthreads(); \
    WRBT32(tid, p0); WRBT32(tid + 512, p1); \
    if (t + 1 < (T)) { \
      const u16* nb = pb + ((size_t)(t + 1) << 13); \
      p0 = *(const uint4*)nb; p1 = *(const uint4*)(nb + 4096); \
    } \
    __syncthreads(); \
    MFMA_STEP32(t) \
  } \
} while (0)

// rows held by this lane: row(rg) = (rg&3) + 8*(rg>>2) + 4*h  (within 32-row half)
#define ROW_OF(rg) (((rg) & 3) + (((rg) >> 2) << 3) + (h << 2))

#define LN_STATS32() do { \
  _Pragma("unroll") \
  for (int rg = 0; rg < 16; ++rg) { \
    float va = accA[rg], vb = accB[rg]; \
    float s = va + vb, s2 = va * va + vb * vb; \
    s  += __shfl_xor(s, 1);  s  += __shfl_xor(s, 2);  s  += __shfl_xor(s, 4); \
    s  += __shfl_xor(s, 8);  s  += __shfl_xor(s, 16); \
    s2 += __shfl_xor(s2, 1); s2 += __shfl_xor(s2, 2); s2 += __shfl_xor(s2, 4); \
    s2 += __shfl_xor(s2, 8); s2 += __shfl_xor(s2, 16); \
    if (m32 == 0) { int mm = wr32 + ROW_OF(rg); red[mm][wc2] = s; red[mm][wc2 + 1] = s2; } \
  } \
  __syncthreads(); \
  if (tid < 64) { \
    float s  = red[tid][0] + red[tid][2] + red[tid][4] + red[tid][6]; \
    float s2 = red[tid][1] + red[tid][3] + red[tid][5] + red[tid][7]; \
    float mu  = s * (1.f / 256.f); \
    float var = s2 * (1.f / 256.f) - mu * mu; \
    murs[tid][0] = mu; murs[tid][1] = rsqrtf(var + 1e-6f); \
  } \
  __syncthreads(); \
} while (0)

__global__ __launch_bounds__(512)
void k_fused(
    const u16* __restrict__ X, const float* __restrict__ nodes,
    const u16* __restrict__ wm, const u16* __restrict__ w0,
    const u16* __restrict__ w1, const u16* __restrict__ w2,
    const float* __restrict__ b0, const float* __restrict__ b1,
    const float* __restrict__ b2,
    const float* __restrict__ lnAs, const float* __restrict__ lnAb,
    const float* __restrict__ lnOs, const float* __restrict__ lnOb,
    float* __restrict__ out)
{
  __shared__ u16 At[64 * 320];     // XOR-swizzled: byte ^= (row&7)<<4
  __shared__ u16 Bt[8192];         // K=32 step: [s][h][n][8]
  __shared__ float red[64][8];
  __shared__ float murs[64][2];

  const int tid = threadIdx.x;
  const int lane = tid & 63;
  const int w = tid >> 6;                // 0..7
  const int wr32 = (w >> 2) << 5;        // row base (0 or 32)
  const int wcn = (w & 3) << 6;          // col base (0,64,128,192)
  const int wc2 = (w & 3) << 1;
  const int m32 = lane & 31, h = lane >> 5;
  const int mrow = wr32 + m32;
  const int r0 = blockIdx.x * 64;

  char* const atb = (char*)At;

  // ---- stage X (bf16, K=320) into swizzled At ----
  #pragma unroll
  for (int it = 0; it < 5; ++it) {
    int c = tid + it * 512;              // 2560 chunks of 16B (exact)
    int r = c / 40, seg = c - r * 40;
    int row = r0 + r;
    uint4 v = {0u, 0u, 0u, 0u};
    if (row < NN) v = *(const uint4*)(X + (size_t)row * 320 + seg * 8);
    *(uint4*)(atb + ((r * 640 + seg * 16) ^ ((r & 7) << 4))) = v;
  }

  f32x16 accA, accB;
  #pragma unroll
  for (int i = 0; i < 16; ++i) { accA[i] = 0.f; accB[i] = 0.f; }

  // ---- GEMM: X @ Wmsg (K=320, 10 steps of 32) ----
  RUN_LAYER32(wm, 10);

  // ---- aggr epilogue: v = relu(acc) + nodes ----
  #pragma unroll
  for (int rg = 0; rg < 16; ++rg) {
    int row = r0 + wr32 + ROW_OF(rg);
    float nA = 0.f, nB = 0.f;
    if (row < NN) {
      nA = nodes[(size_t)row * 256 + wcn + m32];
      nB = nodes[(size_t)row * 256 + wcn + 32 + m32];
    }
    accA[rg] = fmaxf(accA[rg], 0.f) + nA;
    accB[rg] = fmaxf(accB[rg], 0.f) + nB;
  }
  LN_STATS32();                          // barrier inside also fences At reads
  // h = LN_a(v) -> bf16 into At (residual + next A operand)
  {
    float sclA = lnAs[wcn + m32], biaA = lnAb[wcn + m32];
    float sclB = lnAs[wcn + 32 + m32], biaB = lnAb[wcn + 32 + m32];
    #pragma unroll
    for (int rg = 0; rg < 16; ++rg) {
      int mm = wr32 + ROW_OF(rg);
      float mu = murs[mm][0], rs = murs[mm][1];
      float hA = (accA[rg] - mu) * rs * sclA + biaA;
      float hB = (accB[rg] - mu) * rs * sclB + biaB;
      *(u16*)AT_ADDR(mm, wcn + m32) = f2bfu(hA);
      *(u16*)AT_ADDR(mm, wcn + 32 + m32) = f2bfu(hB);
      accA[rg] = 0.f; accB[rg] = 0.f;
    }
  }

  // ---- 3 MLP layers; residual lives in At (bf16) ----
  #pragma unroll 1
  for (int l = 0; l < 3; ++l) {
    const u16* wp = (l == 0) ? w0 : (l == 1) ? w1 : w2;
    RUN_LAYER32(wp, 8);
    __syncthreads();                     // all At MFMA reads done

    if (l < 2) {
      const float* bp = (l == 0) ? b0 : b1;
      float bnA = bp[wcn + m32], bnB = bp[wcn + 32 + m32];
      #pragma unroll
      for (int rg = 0; rg < 16; ++rg) {
        int mm = wr32 + ROW_OF(rg);
        u16* pA = (u16*)AT_ADDR(mm, wcn + m32);
        u16* pB = (u16*)AT_ADDR(mm, wcn + 32 + m32);
        float xA = bf2f(*pA) + fmaxf(accA[rg] + bnA, 0.f);
        float xB = bf2f(*pB) + fmaxf(accB[rg] + bnB, 0.f);
        *pA = f2bfu(xA);                 // owner-thread RMW (disjoint)
        *pB = f2bfu(xB);
        accA[rg] = 0.f; accB[rg] = 0.f;
      }
    } else {
      float bnA = b2[wcn + m32], bnB = b2[wcn + 32 + m32];
      #pragma unroll
      for (int rg = 0; rg < 16; ++rg) {
        int mm = wr32 + ROW_OF(rg);
        int row = r0 + mm;
        float nA = 0.f, nB = 0.f;
        if (row < NN) {
          nA = nodes[(size_t)row * 256 + wcn + m32];
          nB = nodes[(size_t)row * 256 + wcn + 32 + m32];
        }
        accA[rg] = nA + bf2f(*(const u16*)AT_ADDR(mm, wcn + m32)) + accA[rg] + bnA;
        accB[rg] = nB + bf2f(*(const u16*)AT_ADDR(mm, wcn + 32 + m32)) + accB[rg] + bnB;
      }
    }
  }

  // ---- final LayerNorm ----
  LN_STATS32();
  {
    float sclA = lnOs[wcn + m32], biaA = lnOb[wcn + m32];
    float sclB = lnOs[wcn + 32 + m32], biaB = lnOb[wcn + 32 + m32];
    #pragma unroll
    for (int rg = 0; rg < 16; ++rg) {
      int mm = wr32 + ROW_OF(rg);
      int row = r0 + mm;
      if (row < NN) {
        float mu = murs[mm][0], rs = murs[mm][1];
        out[(size_t)row * 256 + wcn + m32] = (accA[rg] - mu) * rs * sclA + biaA;
        out[(size_t)row * 256 + wcn + 32 + m32] = (accB[rg] - mu) * rs * sclB + biaB;
      }
    }
  }
}

// ---------------------------------------------------------------------------
extern "C" void kernel_launch(void* const* d_in, const int* in_sizes, int n_in,
                              void* d_out, int out_size, void* d_ws, size_t ws_size,
                              hipStream_t stream)
{
  const float* nodes = (const float*)d_in[0];
  const float* edges = (const float*)d_in[1];
  const int* senders = (const int*)d_in[2];
  const int* receivers = (const int*)d_in[3];
  const float* Wmsg = (const float*)d_in[4];
  const float* W0 = (const float*)d_in[5];
  const float* b0 = (const float*)d_in[6];
  const float* W1 = (const float*)d_in[7];
  const float* b1 = (const float*)d_in[8];
  const float* W2 = (const float*)d_in[9];
  const float* b2 = (const float*)d_in[10];
  const float* lnAs = (const float*)d_in[11];
  const float* lnAb = (const float*)d_in[12];
  const float* lnOs = (const float*)d_in[13];
  const float* lnOb = (const float*)d_in[14];
  float* out = (float*)d_out;
  (void)in_sizes; (void)n_in; (void)out_size; (void)ws_size;

  char* w = (char*)d_ws;
  size_t off = 0;
  auto take = [&](size_t b) { void* p = w + off; off += (b + 511) & ~(size_t)511; return p; };

  u16*   nodes_bf = (u16*)take((size_t)NN * 256 * 2);
  u16*   wmsg_p   = (u16*)take(320 * 256 * 2);
  u16*   w0_p     = (u16*)take(256 * 256 * 2);
  u16*   w1_p     = (u16*)take(256 * 256 * 2);
  u16*   w2_p     = (u16*)take(256 * 256 * 2);
  u16*   X        = (u16*)take((size_t)NN * 320 * 2);
  int*   cnt      = (int*)take((size_t)NN * 4);
  int*   loc      = (int*)take((size_t)NN * 4);
  int*   offs     = (int*)take((size_t)(NN + 1) * 4);
  int*   cursor   = (int*)take((size_t)NN * 4);
  int2*  s_pair   = (int2*)take((size_t)NE * 8);
  int*   bsum     = (int*)take(256 * 4);
  int*   bpre     = (int*)take(256 * 4);

  const int NB = (NN + 255) / 256;  // 196

  hipMemsetAsync(cnt, 0, (size_t)NN * 4, stream);
  k_prep<<<NB_CVT + NB_PACK + NB_HIST, 256, 0, stream>>>(
      nodes, nodes_bf, Wmsg, W0, W1, W2, wmsg_p, w0_p, w1_p, w2_p,
      receivers, cnt);

  k_scan1<<<NB, 256, 0, stream>>>(cnt, loc, bsum);
  k_scan2<<<1, 256, 0, stream>>>(bsum, bpre, NB);
  k_scan3<<<NB, 256, 0, stream>>>(loc, bpre, offs, cursor);
  k_scatter<<<(NE + 255) / 256, 256, 0, stream>>>(senders, receivers, cursor, s_pair);

  k_aggr<<<NN / 4, 256, 0, stream>>>(nodes_bf, edges, offs, s_pair, X);

  const int MB = (NN + 63) / 64;    // 782
  k_fused<<<MB, 512, 0, stream>>>(X, nodes, wmsg_p, w0_p, w1_p, w2_p,
                                  b0, b1, b2, lnAs, lnAb, lnOs, lnOb, out);
}